// Round 10
// baseline (144.256 us; speedup 1.0000x reference)
//
#include <hip/hip_runtime.h>

// Conv2D 3x3 VALID NHWC, B=16 H=W=224 C=32 F=32 -> [16,222,222,32] fp32.
// im2col GEMM M=788544 K=288 N=32, bf16 MFMA 16x16x32 (swapped: D[filt][pix]).
// Round 10: R9 proved compute-phase LDS/VALU were NOT the path (halving them
// was neutral). Limiter = 1 block/CU lockstep structure: barrier+wait cost
// with nothing to overlap. Fix: 2 blocks/CU.
//  - drop fp32 LDS stage; reg-stage (global->VGPR->perm-pack->ds_write bf16).
//  - single 12-slot bf16 row ring = 63.4 KB LDS -> 2 blocks/CU, 4 waves/SIMD;
//    cross-block overlap fills phase stalls.
//  - ring keeps 1.0x vertical staging (4 new rows/tile); write/read slot
//    sets disjoint mod 12 -> ONE barrier per tile (lgkmcnt only, no vmcnt
//    drain: prefetch regs consumed before barrier, stores need no wait).
//  - T14 order per tile: LOADS(t+2)->regs | compute(t) | CONVERT->ring | bar.

#define HO 222
#define WO 222
#define HIN 224
#define WIN 224
#define CIN 32
#define FOUT 32

#define TW 64                  // output cols per block
#define IC 66                  // staged cols (64 + 2 halo)
#define NT 7                   // tiles per block (4 output rows each)
#define NCHUNK 8               // 4-row stage chunks per block (rows 0..31 rel)
#define GROWS 28               // output rows per block
#define RSLOTS 12              // bf16 ring rows (mod 12)
#define BROWB 5280             // bf16 row bytes (66 px * 80 B)
#define NPAIR 3                // stage pairs per thread (1056 pairs / 512 thr)

typedef __attribute__((ext_vector_type(8))) short short8;
typedef __attribute__((ext_vector_type(4))) float float4v;

__device__ inline short f2bf(float f) {                  // RNE (weights only)
    unsigned u = __builtin_bit_cast(unsigned, f);
    unsigned r = (u + 0x7FFFu + ((u >> 16) & 1u)) >> 16;
    return (short)r;
}

__global__ __launch_bounds__(512, 4) void conv3x3_mfma(
    const float* __restrict__ x,     // [16,224,224,32]
    const float* __restrict__ w,     // [32][288 = (kh,kw,c)]
    const float* __restrict__ bias,  // [32]
    float* __restrict__ out)         // [16,222,222,32]
{
    __shared__ uint4 lds_b16[(RSLOTS * BROWB) / 16];     // 63360 B -> 2 blocks/CU
    char* b16c = reinterpret_cast<char*>(lds_b16);

    const int wot = blockIdx.x;            // 0..3
    const int g   = blockIdx.y;            // 0..7 row groups (28 rows each)
    const int b   = blockIdx.z;            // 0..15
    const int wo_base = wot * TW;
    const int gr0 = g * GROWS;

    const int tid  = threadIdx.x;
    const int lane = tid & 63;
    const int wave = tid >> 6;             // 0..7

    const int fcol = lane & 15;            // A row (filter) / D col (pixel)
    const int kq   = lane >> 4;            // k-slice: k = kq*8 + i

    // ---- weights -> register A-fragments ----
    short8 bfr[2][9];
#pragma unroll
    for (int h = 0; h < 2; ++h) {
        const float* wf = w + (h * 16 + fcol) * 288 + kq * 8;
#pragma unroll
        for (int s = 0; s < 9; ++s) {
            float4 lo = reinterpret_cast<const float4*>(wf + s * 32)[0];
            float4 hi = reinterpret_cast<const float4*>(wf + s * 32)[1];
            short8 v;
            v[0] = f2bf(lo.x); v[1] = f2bf(lo.y); v[2] = f2bf(lo.z); v[3] = f2bf(lo.w);
            v[4] = f2bf(hi.x); v[5] = f2bf(hi.y); v[6] = f2bf(hi.z); v[7] = f2bf(hi.w);
            bfr[h][s] = v;
        }
    }
    const float4 bias0 = reinterpret_cast<const float4*>(bias)[kq];
    const float4 bias1 = reinterpret_cast<const float4*>(bias)[4 + kq];

    // ---- stage chunk cn (4 input rows, 264 px, 1056 16B-pairs) ----
    // pair id: px = id>>2 (row=px/66, col=px%66), sub = id&3 (channels 8sub..+7)
    // i=0,1 always active; i=2 active for tid<32 only.
    auto LOADS = [&](int cn, float4 (*xv)[2]) {
#pragma unroll
        for (int i = 0; i < NPAIR; ++i) {
            if (i < 2 || tid < 32) {
                const int id  = tid + i * 512;
                const int px  = id >> 2;
                const int sub = id & 3;
                const int row = px / IC;
                const int col = px - row * IC;
                int ir  = gr0 + 4 * cn + row; if (ir  > HIN - 1) ir  = HIN - 1;
                int icl = wo_base + col;      if (icl > WIN - 1) icl = WIN - 1;
                const float* src = x + ((b * HIN + ir) * WIN + icl) * CIN + sub * 8;
                xv[i][0] = reinterpret_cast<const float4*>(src)[0];
                xv[i][1] = reinterpret_cast<const float4*>(src)[1];
            }
        }
    };
    auto CONVERT = [&](int cn, float4 (*xv)[2]) {
#pragma unroll
        for (int i = 0; i < NPAIR; ++i) {
            if (i < 2 || tid < 32) {
                const int id  = tid + i * 512;
                const int px  = id >> 2;
                const int sub = id & 3;
                const int row = px / IC;
                const int col = px - row * IC;
                const int slot = (4 * cn + row) % RSLOTS;
                uint4 u0 = __builtin_bit_cast(uint4, xv[i][0]);
                uint4 u1 = __builtin_bit_cast(uint4, xv[i][1]);
                unsigned w0 = __builtin_amdgcn_perm(u0.y, u0.x, 0x07060302u);
                unsigned w1 = __builtin_amdgcn_perm(u0.w, u0.z, 0x07060302u);
                unsigned w2 = __builtin_amdgcn_perm(u1.y, u1.x, 0x07060302u);
                unsigned w3 = __builtin_amdgcn_perm(u1.w, u1.z, 0x07060302u);
                uint4 pk = {w0, w1, w2, w3};
                *reinterpret_cast<uint4*>(
                    b16c + slot * BROWB + col * 80 + sub * 16) = pk;
            }
        }
    };

    // ---------- prologue: chunks 0,1 (both load sets in flight together) ----------
    float4 xvA[NPAIR][2], xvB[NPAIR][2];
    LOADS(0, xvA);
    LOADS(1, xvB);
    CONVERT(0, xvA);
    CONVERT(1, xvB);
    asm volatile("s_waitcnt lgkmcnt(0)" ::: "memory");
    __builtin_amdgcn_sched_barrier(0);
    __builtin_amdgcn_s_barrier();
    __builtin_amdgcn_sched_barrier(0);

    // ---------- main loop: one barrier per tile ----------
    int s0 = 0;                            // (4*t) % 12
#pragma unroll 1
    for (int t = 0; t < NT; ++t) {
        if (t + 2 < NCHUNK) LOADS(t + 2, xvA);   // in flight over compute
        __builtin_amdgcn_sched_barrier(0);

        const int rbase = 4 * t;

#pragma unroll
        for (int j = 0; j < 2; ++j) {
            const int chunk = wave * 2 + j;      // 16 chunks of 16 pixels
            const int pix = chunk * 16 + fcol;
            const int hoo = pix >> 6;            // 0..3
            const int woo = pix & 63;

            float4v acc0 = {0.f, 0.f, 0.f, 0.f};
            float4v acc1 = {0.f, 0.f, 0.f, 0.f};
#pragma unroll
            for (int s = 0; s < 9; ++s) {
                const int kh = s / 3, kw = s % 3;
                int slot = s0 + hoo + kh;        // < 12+5+... max 13
                if (slot >= RSLOTS) slot -= RSLOTS;
                const short8 a = *reinterpret_cast<const short8*>(
                    b16c + slot * BROWB + (woo + kw) * 80 + kq * 16);
                acc0 = __builtin_amdgcn_mfma_f32_16x16x32_bf16(bfr[0][s], a, acc0, 0, 0, 0);
                acc1 = __builtin_amdgcn_mfma_f32_16x16x32_bf16(bfr[1][s], a, acc1, 0, 0, 0);
            }

            // D[filter][pixel]: col(lane&15)=pixel, row=kq*4+r=filter
            const int ho = gr0 + rbase + hoo;
            const int wo = wo_base + woo;
            if (ho < HO && wo < WO) {
                float* o = out + ((b * HO + ho) * WO + wo) * FOUT;
                float4 v0 = {acc0[0] + bias0.x, acc0[1] + bias0.y,
                             acc0[2] + bias0.z, acc0[3] + bias0.w};
                float4 v1 = {acc1[0] + bias1.x, acc1[1] + bias1.y,
                             acc1[2] + bias1.z, acc1[3] + bias1.w};
                reinterpret_cast<float4*>(o)[kq]     = v0;
                reinterpret_cast<float4*>(o)[4 + kq] = v1;
            }
        }

        __builtin_amdgcn_sched_barrier(0);
        // convert chunk t+2 into ring slots (4t+8..11)%12 -- disjoint from
        // compute(t)'s read set (4t..4t+5)%12, so safe while other waves
        // still compute; published by the barrier for compute(t+1).
        if (t + 2 < NCHUNK) CONVERT(t + 2, xvA);

        asm volatile("s_waitcnt lgkmcnt(0)" ::: "memory");
        __builtin_amdgcn_sched_barrier(0);
        __builtin_amdgcn_s_barrier();
        __builtin_amdgcn_sched_barrier(0);

        s0 += 4; if (s0 >= RSLOTS) s0 -= RSLOTS;
    }
}

extern "C" void kernel_launch(void* const* d_in, const int* in_sizes, int n_in,
                              void* d_out, int out_size, void* d_ws, size_t ws_size,
                              hipStream_t stream) {
    const float* x    = (const float*)d_in[0];
    const float* w    = (const float*)d_in[1];
    const float* bias = (const float*)d_in[2];
    float* out        = (float*)d_out;

    dim3 grid(4, 8, 16);    // col-tile, row-group (28 rows), batch = 512 blocks
    dim3 block(512);
    conv3x3_mfma<<<grid, block, 0, stream>>>(x, w, bias, out);
}

// Round 11
// 132.931 us; speedup vs baseline: 1.0852x; 1.0852x over previous
//
#include <hip/hip_runtime.h>

// Conv2D 3x3 VALID NHWC, B=16 H=W=224 C=32 F=32 -> [16,222,222,32] fp32.
// im2col GEMM M=788544 K=288 N=32, bf16 MFMA 16x16x32 (swapped: D[filt][pix]).
// Round 11: R10's structure (bf16 12-slot ring, 63.4 KB LDS -> 2 blocks/CU,
// one barrier/tile) was right but its staging spilled: arrays passed as
// POINTERS into lambdas -> scratch (VGPR=64, WRITE 316 MB of spill). This
// round: six NAMED float4 scalars + inline macros; every index is a
// compile-time constant. Budget: bfr 72 + stage 24 + bias 8 + acc 8 + addr
// ~= 120 <= 128 cap at launch_bounds(512,4).

#define HO 222
#define WO 222
#define HIN 224
#define WIN 224
#define CIN 32
#define FOUT 32

#define TW 64                  // output cols per block
#define IC 66                  // staged cols (64 + 2 halo)
#define NT 7                   // tiles per block (4 output rows each)
#define NCHUNK 8               // 4-row stage chunks per block
#define GROWS 28               // output rows per block
#define RSLOTS 12              // bf16 ring rows (mod 12)
#define BROWB 5280             // bf16 row bytes (66 px * 80 B)

typedef __attribute__((ext_vector_type(8))) short short8;
typedef __attribute__((ext_vector_type(4))) float float4v;

__device__ inline short f2bf(float f) {                  // RNE (weights only)
    unsigned u = __builtin_bit_cast(unsigned, f);
    unsigned r = (u + 0x7FFFu + ((u >> 16) & 1u)) >> 16;
    return (short)r;
}

__global__ __launch_bounds__(512, 4) void conv3x3_mfma(
    const float* __restrict__ x,     // [16,224,224,32]
    const float* __restrict__ w,     // [32][288 = (kh,kw,c)]
    const float* __restrict__ bias,  // [32]
    float* __restrict__ out)         // [16,222,222,32]
{
    __shared__ uint4 lds_b16[(RSLOTS * BROWB) / 16];     // 63360 B -> 2 blocks/CU
    char* b16c = reinterpret_cast<char*>(lds_b16);

    const int wot = blockIdx.x;            // 0..3
    const int g   = blockIdx.y;            // 0..7 row groups (28 rows each)
    const int b   = blockIdx.z;            // 0..15
    const int wo_base = wot * TW;
    const int gr0 = g * GROWS;

    const int tid  = threadIdx.x;
    const int lane = tid & 63;
    const int wave = tid >> 6;             // 0..7

    const int fcol = lane & 15;            // A row (filter) / D col (pixel)
    const int kq   = lane >> 4;            // k-slice: k = kq*8 + i

    // ---- weights -> register A-fragments ----
    short8 bfr[2][9];
#pragma unroll
    for (int h = 0; h < 2; ++h) {
        const float* wf = w + (h * 16 + fcol) * 288 + kq * 8;
#pragma unroll
        for (int s = 0; s < 9; ++s) {
            float4 lo = reinterpret_cast<const float4*>(wf + s * 32)[0];
            float4 hi = reinterpret_cast<const float4*>(wf + s * 32)[1];
            short8 v;
            v[0] = f2bf(lo.x); v[1] = f2bf(lo.y); v[2] = f2bf(lo.z); v[3] = f2bf(lo.w);
            v[4] = f2bf(hi.x); v[5] = f2bf(hi.y); v[6] = f2bf(hi.z); v[7] = f2bf(hi.w);
            bfr[h][s] = v;
        }
    }
    const float4 bias0 = reinterpret_cast<const float4*>(bias)[kq];
    const float4 bias1 = reinterpret_cast<const float4*>(bias)[4 + kq];

    // ---- staging state: six NAMED float4 (never addressable) ----
    float4 sa0, sa1, sb0, sb1, sc0, sc1;

    // pair id -> address of 8 consecutive channels of one staged pixel
#define PAIR_SRC(ID, SRCVAR)                                                  \
    const int px_##SRCVAR  = (ID) >> 2;                                       \
    const int sub_##SRCVAR = (ID) & 3;                                        \
    const int row_##SRCVAR = px_##SRCVAR / IC;                                \
    const int col_##SRCVAR = px_##SRCVAR - row_##SRCVAR * IC;

#define LOADS(CN)                                                             \
    {                                                                         \
        { PAIR_SRC(tid, A)                                                    \
          int ir = gr0 + 4 * (CN) + row_A; if (ir > HIN - 1) ir = HIN - 1;    \
          int ic = wo_base + col_A;        if (ic > WIN - 1) ic = WIN - 1;    \
          const float* s_ = x + ((b * HIN + ir) * WIN + ic) * CIN + sub_A * 8;\
          sa0 = reinterpret_cast<const float4*>(s_)[0];                       \
          sa1 = reinterpret_cast<const float4*>(s_)[1]; }                     \
        { PAIR_SRC(tid + 512, B)                                              \
          int ir = gr0 + 4 * (CN) + row_B; if (ir > HIN - 1) ir = HIN - 1;    \
          int ic = wo_base + col_B;        if (ic > WIN - 1) ic = WIN - 1;    \
          const float* s_ = x + ((b * HIN + ir) * WIN + ic) * CIN + sub_B * 8;\
          sb0 = reinterpret_cast<const float4*>(s_)[0];                       \
          sb1 = reinterpret_cast<const float4*>(s_)[1]; }                     \
        if (tid < 32) {                                                       \
          PAIR_SRC(tid + 1024, C)                                             \
          int ir = gr0 + 4 * (CN) + row_C; if (ir > HIN - 1) ir = HIN - 1;    \
          int ic = wo_base + col_C;        if (ic > WIN - 1) ic = WIN - 1;    \
          const float* s_ = x + ((b * HIN + ir) * WIN + ic) * CIN + sub_C * 8;\
          sc0 = reinterpret_cast<const float4*>(s_)[0];                       \
          sc1 = reinterpret_cast<const float4*>(s_)[1]; }                     \
    }

#define PACK_WRITE(CN, V0, V1, ID)                                            \
    {                                                                         \
        PAIR_SRC(ID, W)                                                       \
        const int slot = (4 * (CN) + row_W) % RSLOTS;                         \
        uint4 u0 = __builtin_bit_cast(uint4, V0);                             \
        uint4 u1 = __builtin_bit_cast(uint4, V1);                             \
        unsigned w0 = __builtin_amdgcn_perm(u0.y, u0.x, 0x07060302u);         \
        unsigned w1 = __builtin_amdgcn_perm(u0.w, u0.z, 0x07060302u);         \
        unsigned w2 = __builtin_amdgcn_perm(u1.y, u1.x, 0x07060302u);         \
        unsigned w3 = __builtin_amdgcn_perm(u1.w, u1.z, 0x07060302u);         \
        uint4 pk = {w0, w1, w2, w3};                                          \
        *reinterpret_cast<uint4*>(                                            \
            b16c + slot * BROWB + col_W * 80 + sub_W * 16) = pk;              \
    }

#define CONVERT(CN)                                                           \
    {                                                                         \
        PACK_WRITE(CN, sa0, sa1, tid)                                         \
        PACK_WRITE(CN, sb0, sb1, tid + 512)                                   \
        if (tid < 32) { PACK_WRITE(CN, sc0, sc1, tid + 1024) }                \
    }

    // ---------- prologue: chunks 0,1 serially through the one reg set ----------
    LOADS(0);
    CONVERT(0);
    LOADS(1);
    CONVERT(1);
    asm volatile("s_waitcnt lgkmcnt(0)" ::: "memory");
    __builtin_amdgcn_sched_barrier(0);
    __builtin_amdgcn_s_barrier();
    __builtin_amdgcn_sched_barrier(0);

    // ---------- main loop: one barrier per tile ----------
    int s0 = 0;                            // (4*t) % 12
#pragma unroll 1
    for (int t = 0; t < NT; ++t) {
        if (t + 2 < NCHUNK) LOADS(t + 2);  // loads in flight over compute
        __builtin_amdgcn_sched_barrier(0);

        const int rbase = 4 * t;

#pragma unroll
        for (int j = 0; j < 2; ++j) {
            const int chunk = wave * 2 + j;      // 16 chunks of 16 pixels
            const int pix = chunk * 16 + fcol;
            const int hoo = pix >> 6;            // 0..3
            const int woo = pix & 63;

            float4v acc0 = {0.f, 0.f, 0.f, 0.f};
            float4v acc1 = {0.f, 0.f, 0.f, 0.f};
#pragma unroll
            for (int s = 0; s < 9; ++s) {
                const int kh = s / 3, kw = s % 3;
                int slot = s0 + hoo + kh;        // max 13
                if (slot >= RSLOTS) slot -= RSLOTS;
                const short8 a = *reinterpret_cast<const short8*>(
                    b16c + slot * BROWB + (woo + kw) * 80 + kq * 16);
                acc0 = __builtin_amdgcn_mfma_f32_16x16x32_bf16(bfr[0][s], a, acc0, 0, 0, 0);
                acc1 = __builtin_amdgcn_mfma_f32_16x16x32_bf16(bfr[1][s], a, acc1, 0, 0, 0);
            }

            // D[filter][pixel]: col(lane&15)=pixel, row=kq*4+r=filter
            const int ho = gr0 + rbase + hoo;
            const int wo = wo_base + woo;
            if (ho < HO && wo < WO) {
                float* o = out + ((b * HO + ho) * WO + wo) * FOUT;
                float4 v0 = {acc0[0] + bias0.x, acc0[1] + bias0.y,
                             acc0[2] + bias0.z, acc0[3] + bias0.w};
                float4 v1 = {acc1[0] + bias1.x, acc1[1] + bias1.y,
                             acc1[2] + bias1.z, acc1[3] + bias1.w};
                reinterpret_cast<float4*>(o)[kq]     = v0;
                reinterpret_cast<float4*>(o)[4 + kq] = v1;
            }
        }

        __builtin_amdgcn_sched_barrier(0);
        // convert chunk t+2 into slots (4t+8..11)%12, disjoint from
        // compute(t)'s read set (4t..4t+5)%12; published by the barrier.
        if (t + 2 < NCHUNK) CONVERT(t + 2);

        asm volatile("s_waitcnt lgkmcnt(0)" ::: "memory");
        __builtin_amdgcn_sched_barrier(0);
        __builtin_amdgcn_s_barrier();
        __builtin_amdgcn_sched_barrier(0);

        s0 += 4; if (s0 >= RSLOTS) s0 -= RSLOTS;
    }
#undef LOADS
#undef CONVERT
#undef PACK_WRITE
#undef PAIR_SRC
}

extern "C" void kernel_launch(void* const* d_in, const int* in_sizes, int n_in,
                              void* d_out, int out_size, void* d_ws, size_t ws_size,
                              hipStream_t stream) {
    const float* x    = (const float*)d_in[0];
    const float* w    = (const float*)d_in[1];
    const float* bias = (const float*)d_in[2];
    float* out        = (float*)d_out;

    dim3 grid(4, 8, 16);    // col-tile, row-group (28 rows), batch = 512 blocks
    dim3 block(512);
    conv3x3_mfma<<<grid, block, 0, stream>>>(x, w, bias, out);
}

// Round 12
// 54.902 us; speedup vs baseline: 2.6275x; 2.4212x over previous
//
#include <hip/hip_runtime.h>

// Conv2D 3x3 VALID NHWC, B=16 H=W=224 C=32 F=32 -> [16,222,222,32] fp32.
// im2col GEMM M=788544 K=288 N=32, bf16 MFMA 16x16x32 (swapped: D[filt][pix]).
// Round 12: A/B on the spill cause. Every __launch_bounds__(512,4) round
// (R2,R3,R4,R10,R11) reports VGPR_Count=64 + scratch traffic; every (512,2)
// round (R5-R9) reports 100-128 and clean writes. (512,4) imposes a 64-VGPR
// cap -> the ~120-reg working set (bfr 72 + stage 24 + bias 8 + addr) MUST
// spill. Same kernel as R11, launch_bounds (512,2): cap 128, no spill, and
// LDS 63.4 KB + VGPR<=128 still allow 2 blocks/CU naturally.

#define HO 222
#define WO 222
#define HIN 224
#define WIN 224
#define CIN 32
#define FOUT 32

#define TW 64                  // output cols per block
#define IC 66                  // staged cols (64 + 2 halo)
#define NT 7                   // tiles per block (4 output rows each)
#define NCHUNK 8               // 4-row stage chunks per block
#define GROWS 28               // output rows per block
#define RSLOTS 12              // bf16 ring rows (mod 12)
#define BROWB 5280             // bf16 row bytes (66 px * 80 B)

typedef __attribute__((ext_vector_type(8))) short short8;
typedef __attribute__((ext_vector_type(4))) float float4v;

__device__ inline short f2bf(float f) {                  // RNE (weights only)
    unsigned u = __builtin_bit_cast(unsigned, f);
    unsigned r = (u + 0x7FFFu + ((u >> 16) & 1u)) >> 16;
    return (short)r;
}

__global__ __launch_bounds__(512, 2) void conv3x3_mfma(
    const float* __restrict__ x,     // [16,224,224,32]
    const float* __restrict__ w,     // [32][288 = (kh,kw,c)]
    const float* __restrict__ bias,  // [32]
    float* __restrict__ out)         // [16,222,222,32]
{
    __shared__ uint4 lds_b16[(RSLOTS * BROWB) / 16];     // 63360 B -> 2 blocks/CU
    char* b16c = reinterpret_cast<char*>(lds_b16);

    const int wot = blockIdx.x;            // 0..3
    const int g   = blockIdx.y;            // 0..7 row groups (28 rows each)
    const int b   = blockIdx.z;            // 0..15
    const int wo_base = wot * TW;
    const int gr0 = g * GROWS;

    const int tid  = threadIdx.x;
    const int lane = tid & 63;
    const int wave = tid >> 6;             // 0..7

    const int fcol = lane & 15;            // A row (filter) / D col (pixel)
    const int kq   = lane >> 4;            // k-slice: k = kq*8 + i

    // ---- weights -> register A-fragments ----
    short8 bfr[2][9];
#pragma unroll
    for (int h = 0; h < 2; ++h) {
        const float* wf = w + (h * 16 + fcol) * 288 + kq * 8;
#pragma unroll
        for (int s = 0; s < 9; ++s) {
            float4 lo = reinterpret_cast<const float4*>(wf + s * 32)[0];
            float4 hi = reinterpret_cast<const float4*>(wf + s * 32)[1];
            short8 v;
            v[0] = f2bf(lo.x); v[1] = f2bf(lo.y); v[2] = f2bf(lo.z); v[3] = f2bf(lo.w);
            v[4] = f2bf(hi.x); v[5] = f2bf(hi.y); v[6] = f2bf(hi.z); v[7] = f2bf(hi.w);
            bfr[h][s] = v;
        }
    }
    const float4 bias0 = reinterpret_cast<const float4*>(bias)[kq];
    const float4 bias1 = reinterpret_cast<const float4*>(bias)[4 + kq];

    // ---- staging state: six NAMED float4 (never addressable) ----
    float4 sa0, sa1, sb0, sb1, sc0, sc1;

#define PAIR_SRC(ID, SRCVAR)                                                  \
    const int px_##SRCVAR  = (ID) >> 2;                                       \
    const int sub_##SRCVAR = (ID) & 3;                                        \
    const int row_##SRCVAR = px_##SRCVAR / IC;                                \
    const int col_##SRCVAR = px_##SRCVAR - row_##SRCVAR * IC;

#define LOADS(CN)                                                             \
    {                                                                         \
        { PAIR_SRC(tid, A)                                                    \
          int ir = gr0 + 4 * (CN) + row_A; if (ir > HIN - 1) ir = HIN - 1;    \
          int ic = wo_base + col_A;        if (ic > WIN - 1) ic = WIN - 1;    \
          const float* s_ = x + ((b * HIN + ir) * WIN + ic) * CIN + sub_A * 8;\
          sa0 = reinterpret_cast<const float4*>(s_)[0];                       \
          sa1 = reinterpret_cast<const float4*>(s_)[1]; }                     \
        { PAIR_SRC(tid + 512, B)                                              \
          int ir = gr0 + 4 * (CN) + row_B; if (ir > HIN - 1) ir = HIN - 1;    \
          int ic = wo_base + col_B;        if (ic > WIN - 1) ic = WIN - 1;    \
          const float* s_ = x + ((b * HIN + ir) * WIN + ic) * CIN + sub_B * 8;\
          sb0 = reinterpret_cast<const float4*>(s_)[0];                       \
          sb1 = reinterpret_cast<const float4*>(s_)[1]; }                     \
        if (tid < 32) {                                                       \
          PAIR_SRC(tid + 1024, C)                                             \
          int ir = gr0 + 4 * (CN) + row_C; if (ir > HIN - 1) ir = HIN - 1;    \
          int ic = wo_base + col_C;        if (ic > WIN - 1) ic = WIN - 1;    \
          const float* s_ = x + ((b * HIN + ir) * WIN + ic) * CIN + sub_C * 8;\
          sc0 = reinterpret_cast<const float4*>(s_)[0];                       \
          sc1 = reinterpret_cast<const float4*>(s_)[1]; }                     \
    }

#define PACK_WRITE(CN, V0, V1, ID)                                            \
    {                                                                         \
        PAIR_SRC(ID, W)                                                       \
        const int slot = (4 * (CN) + row_W) % RSLOTS;                         \
        uint4 u0 = __builtin_bit_cast(uint4, V0);                             \
        uint4 u1 = __builtin_bit_cast(uint4, V1);                             \
        unsigned w0 = __builtin_amdgcn_perm(u0.y, u0.x, 0x07060302u);         \
        unsigned w1 = __builtin_amdgcn_perm(u0.w, u0.z, 0x07060302u);         \
        unsigned w2 = __builtin_amdgcn_perm(u1.y, u1.x, 0x07060302u);         \
        unsigned w3 = __builtin_amdgcn_perm(u1.w, u1.z, 0x07060302u);         \
        uint4 pk = {w0, w1, w2, w3};                                          \
        *reinterpret_cast<uint4*>(                                            \
            b16c + slot * BROWB + col_W * 80 + sub_W * 16) = pk;              \
    }

#define CONVERT(CN)                                                           \
    {                                                                         \
        PACK_WRITE(CN, sa0, sa1, tid)                                         \
        PACK_WRITE(CN, sb0, sb1, tid + 512)                                   \
        if (tid < 32) { PACK_WRITE(CN, sc0, sc1, tid + 1024) }                \
    }

    // ---------- prologue: chunks 0,1 serially through the one reg set ----------
    LOADS(0);
    CONVERT(0);
    LOADS(1);
    CONVERT(1);
    asm volatile("s_waitcnt lgkmcnt(0)" ::: "memory");
    __builtin_amdgcn_sched_barrier(0);
    __builtin_amdgcn_s_barrier();
    __builtin_amdgcn_sched_barrier(0);

    // ---------- main loop: one barrier per tile ----------
    int s0 = 0;                            // (4*t) % 12
#pragma unroll 1
    for (int t = 0; t < NT; ++t) {
        if (t + 2 < NCHUNK) LOADS(t + 2);  // loads in flight over compute
        __builtin_amdgcn_sched_barrier(0);

        const int rbase = 4 * t;

#pragma unroll
        for (int j = 0; j < 2; ++j) {
            const int chunk = wave * 2 + j;      // 16 chunks of 16 pixels
            const int pix = chunk * 16 + fcol;
            const int hoo = pix >> 6;            // 0..3
            const int woo = pix & 63;

            float4v acc0 = {0.f, 0.f, 0.f, 0.f};
            float4v acc1 = {0.f, 0.f, 0.f, 0.f};
#pragma unroll
            for (int s = 0; s < 9; ++s) {
                const int kh = s / 3, kw = s % 3;
                int slot = s0 + hoo + kh;        // max 13
                if (slot >= RSLOTS) slot -= RSLOTS;
                const short8 a = *reinterpret_cast<const short8*>(
                    b16c + slot * BROWB + (woo + kw) * 80 + kq * 16);
                acc0 = __builtin_amdgcn_mfma_f32_16x16x32_bf16(bfr[0][s], a, acc0, 0, 0, 0);
                acc1 = __builtin_amdgcn_mfma_f32_16x16x32_bf16(bfr[1][s], a, acc1, 0, 0, 0);
            }

            // D[filter][pixel]: col(lane&15)=pixel, row=kq*4+r=filter
            const int ho = gr0 + rbase + hoo;
            const int wo = wo_base + woo;
            if (ho < HO && wo < WO) {
                float* o = out + ((b * HO + ho) * WO + wo) * FOUT;
                float4 v0 = {acc0[0] + bias0.x, acc0[1] + bias0.y,
                             acc0[2] + bias0.z, acc0[3] + bias0.w};
                float4 v1 = {acc1[0] + bias1.x, acc1[1] + bias1.y,
                             acc1[2] + bias1.z, acc1[3] + bias1.w};
                reinterpret_cast<float4*>(o)[kq]     = v0;
                reinterpret_cast<float4*>(o)[4 + kq] = v1;
            }
        }

        __builtin_amdgcn_sched_barrier(0);
        // convert chunk t+2 into slots (4t+8..11)%12, disjoint from
        // compute(t)'s read set (4t..4t+5)%12; published by the barrier.
        if (t + 2 < NCHUNK) CONVERT(t + 2);

        asm volatile("s_waitcnt lgkmcnt(0)" ::: "memory");
        __builtin_amdgcn_sched_barrier(0);
        __builtin_amdgcn_s_barrier();
        __builtin_amdgcn_sched_barrier(0);

        s0 += 4; if (s0 >= RSLOTS) s0 -= RSLOTS;
    }
#undef LOADS
#undef CONVERT
#undef PACK_WRITE
#undef PAIR_SRC
}

extern "C" void kernel_launch(void* const* d_in, const int* in_sizes, int n_in,
                              void* d_out, int out_size, void* d_ws, size_t ws_size,
                              hipStream_t stream) {
    const float* x    = (const float*)d_in[0];
    const float* w    = (const float*)d_in[1];
    const float* bias = (const float*)d_in[2];
    float* out        = (float*)d_out;

    dim3 grid(4, 8, 16);    // col-tile, row-group (28 rows), batch = 512 blocks
    dim3 block(512);
    conv3x3_mfma<<<grid, block, 0, stream>>>(x, w, bias, out);
}